// Round 3
// baseline (1382.453 us; speedup 1.0000x reference)
//
#include <hip/hip_runtime.h>
#include <hip/hip_bf16.h>

// FlashFFN: y = nan_to_num(gelu_tanh(x@W1 + b1) @ W2) + b2
// Round 5: cross-phase software-pipelined ds_reads with COUNTED lgkmcnt.
// Round 4's asm reads removed the compiler's vmcnt(0) drains but kept
// per-phase [reads -> barrier -> lgkmcnt(0) -> MFMA] serialization: LDS
// servicing and MFMA never overlap. Now fragment reads are issued one phase
// ahead (grpR(t) at top of phase A, grpP/Q(t+1) mid-phase-B after a
// relocated vmcnt(8)+barrier residency point) and waited with counted
// lgkmcnt(4)/(8) so the newest group stays in flight under the MFMA cluster.
// B-fragments live across both phases -> register double-buffer via manual
// 2x loop unroll (all reg indices compile-time). 3 barriers/tile (was 4).

using bf16 = __hip_bfloat16;
typedef __attribute__((ext_vector_type(4))) float floatx4;
typedef __attribute__((ext_vector_type(8))) short shortx8;

#define TOKENS 4096   // B*S = 2*2048
#define DMODEL 4096
#define DFF    16384

__device__ __forceinline__ void gload_lds16(const void* g, void* l) {
  __builtin_amdgcn_global_load_lds(
      (const __attribute__((address_space(1))) unsigned int*)g,
      (__attribute__((address_space(3))) unsigned int*)l,
      16, 0, 0);
}

__device__ __forceinline__ unsigned lds_u32(const void* p) {
  return (unsigned)(unsigned long long)(const __attribute__((address_space(3))) char*)p;
}

__device__ __forceinline__ float gelu_tanh(float x) {
  // JAX default gelu (approximate=True, tanh form)
  float z = 0.7978845608028654f * (x + 0.044715f * x * x * x);
  float e = __expf(2.0f * z);   // inf -> t=1, 0 -> t=-1: both limits correct
  float t = 1.0f - 2.0f / (e + 1.0f);
  return 0.5f * x * (1.0f + t);
}

// ---- pre-pass: f32 -> bf16 cast (layout preserved), 8 elems/thread ----
__global__ void cvt_f32_bf16(const float* __restrict__ in, bf16* __restrict__ out) {
  int i = (blockIdx.x * blockDim.x + threadIdx.x) * 8;
  float4 a = *(const float4*)(in + i);
  float4 b = *(const float4*)(in + i + 4);
  union { shortx8 v; bf16 h[8]; } r;
  r.h[0] = __float2bfloat16(a.x); r.h[1] = __float2bfloat16(a.y);
  r.h[2] = __float2bfloat16(a.z); r.h[3] = __float2bfloat16(a.w);
  r.h[4] = __float2bfloat16(b.x); r.h[5] = __float2bfloat16(b.y);
  r.h[6] = __float2bfloat16(b.z); r.h[7] = __float2bfloat16(b.w);
  *(shortx8*)(out + i) = r.v;
}

// ---- pre-pass: transpose + cast. in [R][C] f32 -> out [C][R] bf16 ----
__global__ void transpose_cvt(const float* __restrict__ in, bf16* __restrict__ out,
                              int R, int C) {
  __shared__ float tile[64][65];
  const int c0 = blockIdx.x * 64, r0 = blockIdx.y * 64;
  const int t = threadIdx.x;
#pragma unroll
  for (int p = 0; p < 4; ++p) {
    int r = p * 16 + (t >> 4);
    int c = (t & 15) * 4;
    float4 v = *(const float4*)(in + (size_t)(r0 + r) * C + c0 + c);
    tile[r][c] = v.x; tile[r][c + 1] = v.y;
    tile[r][c + 2] = v.z; tile[r][c + 3] = v.w;
  }
  __syncthreads();
#pragma unroll
  for (int p = 0; p < 2; ++p) {
    int c = p * 32 + (t >> 3);
    int rb = (t & 7) * 8;
    union { shortx8 v; bf16 h[8]; } u;
#pragma unroll
    for (int j = 0; j < 8; ++j) u.h[j] = __float2bfloat16(tile[rb + j][c]);
    *(shortx8*)(out + (size_t)(c0 + c) * R + r0 + rb) = u.v;
  }
}

// ---- deep-pipelined GEMM: C = A @ Bt^T ----
// A [M][K] bf16 row-major, Bt [N][K] bf16 row-major. 256x256 tile, BK=32,
// 8 waves (2Mx4N), wave = 128x64 output via 8x4 16x16x32 MFMAs per K-tile.
// LDS ring: 4 slots x (256x32 A + 256x32 B). Staging swizzle (proven r2-r4):
// lane L covers row L>>2, src 16B-block (L&3)^((L>>3)&3); LDS linear.
//
// Per-tile schedule (see hazard ledger in session notes):
//  phA: gloadA(t+3) | issue grpR(t) | lgkm(4) [grpP/Q(t) done, grpR flies]
//       | MFMA A | BAR1
//  phB: gloadB(t+3) | vmcnt(8) BAR2 [tile t+1 resident globally]
//       | issue grpP/Q(t+1) | lgkm(8) [grpR(t) done, grpP/Q(t+1) flies]
//       | MFMA B | BAR3
#define TILE_BODY(T, BC, BN)                                                     \
  {                                                                              \
    const int t_ = (T);                                                          \
    const unsigned aslot = As0 + (unsigned)(t_ & 3) * 16384u + a_foff;           \
    /* ---------------- phase A ---------------- */                              \
    if (t_ + 3 < NT) {                                                           \
      bf16* al = alw + ((t_ + 3) & 3) * 8192;                                    \
      const bf16* ag = agp + (size_t)(t_ + 3) * 32;                              \
      gload_lds16(ag, al);                                                       \
      gload_lds16(ag + 16 * Ks, al + 512);                                       \
    }                                                                            \
    asm volatile("ds_read_b128 %0, %1 offset:4096" : "=v"(cF[0]) : "v"(aslot)); \
    asm volatile("ds_read_b128 %0, %1 offset:5120" : "=v"(cF[1]) : "v"(aslot)); \
    asm volatile("ds_read_b128 %0, %1 offset:6144" : "=v"(cF[2]) : "v"(aslot)); \
    asm volatile("ds_read_b128 %0, %1 offset:7168" : "=v"(cF[3]) : "v"(aslot)); \
    asm volatile("s_waitcnt lgkmcnt(4)");                                        \
    __builtin_amdgcn_sched_barrier(0);                                           \
    __builtin_amdgcn_s_setprio(1);                                               \
    _Pragma("unroll")                                                            \
    for (int mi = 0; mi < 4; ++mi)                                               \
      _Pragma("unroll")                                                          \
      for (int ni = 0; ni < 4; ++ni)                                             \
        acc[mi][ni] = __builtin_amdgcn_mfma_f32_16x16x32_bf16(                   \
            aF[mi], bB[BC][ni], acc[mi][ni], 0, 0, 0);                           \
    __builtin_amdgcn_s_setprio(0);                                               \
    __builtin_amdgcn_sched_barrier(0);                                           \
    __builtin_amdgcn_s_barrier(); /* BAR1 */                                     \
    /* ---------------- phase B ---------------- */                              \
    if (t_ + 3 < NT) {                                                           \
      bf16* bl = blw + ((t_ + 3) & 3) * 8192;                                    \
      const bf16* bg = bgp + (size_t)(t_ + 3) * 32;                              \
      gload_lds16(bg, bl);                                                       \
      gload_lds16(bg + 16 * Ks, bl + 512);                                       \
    }                                                                            \
    if (t_ + 1 < NT) {                                                           \
      if (t_ + 3 < NT)      asm volatile("s_waitcnt vmcnt(8)");                  \
      else if (t_ + 2 < NT) asm volatile("s_waitcnt vmcnt(4)");                  \
      else                  asm volatile("s_waitcnt vmcnt(0)");                  \
      __builtin_amdgcn_s_barrier(); /* BAR2: tile t+1 resident globally */       \
      const unsigned an = As0 + (unsigned)((t_ + 1) & 3) * 16384u + a_foff;      \
      const unsigned bn = Bs0 + (unsigned)((t_ + 1) & 3) * 16384u + b_foff;      \
      asm volatile("ds_read_b128 %0, %1 offset:0"    : "=v"(aF[0]) : "v"(an));   \
      asm volatile("ds_read_b128 %0, %1 offset:1024" : "=v"(aF[1]) : "v"(an));   \
      asm volatile("ds_read_b128 %0, %1 offset:2048" : "=v"(aF[2]) : "v"(an));   \
      asm volatile("ds_read_b128 %0, %1 offset:3072" : "=v"(aF[3]) : "v"(an));   \
      asm volatile("ds_read_b128 %0, %1 offset:0"    : "=v"(bB[BN][0]) : "v"(bn)); \
      asm volatile("ds_read_b128 %0, %1 offset:1024" : "=v"(bB[BN][1]) : "v"(bn)); \
      asm volatile("ds_read_b128 %0, %1 offset:2048" : "=v"(bB[BN][2]) : "v"(bn)); \
      asm volatile("ds_read_b128 %0, %1 offset:3072" : "=v"(bB[BN][3]) : "v"(bn)); \
      asm volatile("s_waitcnt lgkmcnt(8)");                                      \
    } else {                                                                     \
      asm volatile("s_waitcnt lgkmcnt(0)");                                      \
    }                                                                            \
    __builtin_amdgcn_sched_barrier(0);                                           \
    __builtin_amdgcn_s_setprio(1);                                               \
    _Pragma("unroll")                                                            \
    for (int mi = 0; mi < 4; ++mi)                                               \
      _Pragma("unroll")                                                          \
      for (int ni = 0; ni < 4; ++ni)                                             \
        acc[4 + mi][ni] = __builtin_amdgcn_mfma_f32_16x16x32_bf16(               \
            cF[mi], bB[BC][ni], acc[4 + mi][ni], 0, 0, 0);                       \
    __builtin_amdgcn_s_setprio(0);                                               \
    __builtin_amdgcn_sched_barrier(0);                                           \
    __builtin_amdgcn_s_barrier(); /* BAR3 */                                     \
  }

template <int FUSE_GELU>
__launch_bounds__(512, 2)
__global__ void gemm_bt(const bf16* __restrict__ A, const bf16* __restrict__ Bt,
                        const float* __restrict__ bias, void* __restrict__ Cout,
                        int M, int N, int K) {
  __shared__ __align__(16) bf16 As[4 * 256 * 32];   // 64 KiB
  __shared__ __align__(16) bf16 Bs[4 * 256 * 32];   // 64 KiB

  const int tid = threadIdx.x;
  const int wave = tid >> 6;
  const int lane = tid & 63;

  // T1: bijective XCD swizzle (nwg % 8 == 0 for both GEMMs: 1024 / 256)
  const int nbx = N >> 8;
  const int nwg = gridDim.x;
  const int chunk = nwg >> 3;
  const int wg = (blockIdx.x & 7) * chunk + (blockIdx.x >> 3);
  const int n0 = (wg % nbx) * 256;
  const int m0 = (wg / nbx) * 256;

  const size_t Ks = (size_t)K;
  const int NT = K >> 5;   // # of BK=32 K-tiles (128 or 512 here; even)

  const int srow = lane >> 2;
  const int kbsw = (lane & 3) ^ ((lane >> 3) & 3);
  const bf16* agp = A  + (size_t)(m0 + wave * 32 + srow) * Ks + kbsw * 8;
  const bf16* bgp = Bt + (size_t)(n0 + wave * 32 + srow) * Ks + kbsw * 8;
  bf16* const alw = As + wave * 1024;   // 32 rows * 32 cols
  bf16* const blw = Bs + wave * 1024;

  // fragment-read constants (16x16x32 MFMA)
  const int wr = wave >> 2, wc = wave & 3;
  const int wm = wr * 128, wn = wc * 64;
  const int fr = lane & 15;            // row within 16-row fragment
  const int q  = lane >> 4;            // which 8-elem k-block (0..3)
  const int sf = (fr >> 1) & 3;        // matches staging swizzle s(row)
  const int fk = (q ^ sf) * 8;

  const unsigned As0 = lds_u32(As);
  const unsigned Bs0 = lds_u32(Bs);
  const unsigned a_foff = (unsigned)((wm + fr) * 32 + fk) * 2;
  const unsigned b_foff = (unsigned)((wn + fr) * 32 + fk) * 2;

  floatx4 acc[8][4] = {};
  shortx8 aF[4];      // grpP: A mi0-3 of current tile
  shortx8 cF[4];      // grpR: A mi4-7 of current tile
  shortx8 bB[2][4];   // grpQ: B ni0-3, register double-buffer across tiles

  // prologue: stage K-tiles 0..2 into ring slots 0..2 (12 loads/thread)
#pragma unroll
  for (int pt = 0; pt < 3; ++pt) {
    bf16* al = alw + pt * 8192;
    bf16* bl = blw + pt * 8192;
    const bf16* ag = agp + (size_t)pt * 32;
    const bf16* bg = bgp + (size_t)pt * 32;
    gload_lds16(ag, al);
    gload_lds16(ag + 16 * Ks, al + 512);
    gload_lds16(bg, bl);
    gload_lds16(bg + 16 * Ks, bl + 512);
  }
  asm volatile("s_waitcnt vmcnt(8)");   // tile 0 resident (own loads)
  __builtin_amdgcn_s_barrier();         // tile 0 resident globally
  {
    const unsigned a0 = As0 + a_foff;   // slot 0
    const unsigned b0 = Bs0 + b_foff;
    asm volatile("ds_read_b128 %0, %1 offset:0"    : "=v"(aF[0]) : "v"(a0));
    asm volatile("ds_read_b128 %0, %1 offset:1024" : "=v"(aF[1]) : "v"(a0));
    asm volatile("ds_read_b128 %0, %1 offset:2048" : "=v"(aF[2]) : "v"(a0));
    asm volatile("ds_read_b128 %0, %1 offset:3072" : "=v"(aF[3]) : "v"(a0));
    asm volatile("ds_read_b128 %0, %1 offset:0"    : "=v"(bB[0][0]) : "v"(b0));
    asm volatile("ds_read_b128 %0, %1 offset:1024" : "=v"(bB[0][1]) : "v"(b0));
    asm volatile("ds_read_b128 %0, %1 offset:2048" : "=v"(bB[0][2]) : "v"(b0));
    asm volatile("ds_read_b128 %0, %1 offset:3072" : "=v"(bB[0][3]) : "v"(b0));
  }

  for (int t = 0; t < NT; t += 2) {
    TILE_BODY(t,     0, 1)
    TILE_BODY(t + 1, 1, 0)
  }

  // epilogue. C/D layout (m89/m91): col = lane&15, row = (lane>>4)*4 + reg
  const int col0 = n0 + wn + fr;
  const int row0 = m0 + wm + (lane >> 4) * 4;
#pragma unroll
  for (int ni = 0; ni < 4; ++ni) {
    const int col = col0 + ni * 16;
    const float bv = bias[col];
#pragma unroll
    for (int mi = 0; mi < 8; ++mi) {
#pragma unroll
      for (int r = 0; r < 4; ++r) {
        const int row = row0 + mi * 16 + r;
        float v = acc[mi][ni][r];
        if (FUSE_GELU) {
          v = gelu_tanh(v + bv);
          ((bf16*)Cout)[(size_t)row * N + col] = __float2bfloat16(v);
        } else {
          if (!isfinite(v)) v = 0.0f;   // nan_to_num BEFORE +b2
          ((float*)Cout)[(size_t)row * N + col] = v + bv;
        }
      }
    }
  }
}

extern "C" void kernel_launch(void* const* d_in, const int* in_sizes, int n_in,
                              void* d_out, int out_size, void* d_ws, size_t ws_size,
                              hipStream_t stream) {
  const float* x  = (const float*)d_in[0];
  const float* W1 = (const float*)d_in[1];
  const float* b1 = (const float*)d_in[2];
  const float* W2 = (const float*)d_in[3];
  const float* b2 = (const float*)d_in[4];
  float* out = (float*)d_out;

  // workspace layout (bf16): xb 32MB @0, h 128MB @32MB, w1t 128MB @160MB,
  // w2t 128MB @288MB (total 416 MB)
  char* ws = (char*)d_ws;
  bf16* xb  = (bf16*)(ws);
  bf16* h   = (bf16*)(ws + (size_t)32  * 1024 * 1024);
  bf16* w1t = (bf16*)(ws + (size_t)160 * 1024 * 1024);
  bf16* w2t = (bf16*)(ws + (size_t)288 * 1024 * 1024);

  cvt_f32_bf16<<<(TOKENS * DMODEL / 8) / 256, 256, 0, stream>>>(x, xb);
  transpose_cvt<<<dim3(DFF / 64, DMODEL / 64), 256, 0, stream>>>(W1, w1t, DMODEL, DFF);
  transpose_cvt<<<dim3(DMODEL / 64, DFF / 64), 256, 0, stream>>>(W2, w2t, DFF, DMODEL);

  // GEMM1: h = gelu(x @ W1 + b1)   [4096 x 16384] bf16
  gemm_bt<1><<<dim3((DFF / 256) * (TOKENS / 256)), 512, 0, stream>>>(
      xb, w1t, b1, h, TOKENS, DFF, DMODEL);

  // GEMM2: out = nan_guard(h @ W2) + b2   [4096 x 4096] f32
  gemm_bt<0><<<dim3((DMODEL / 256) * (TOKENS / 256)), 512, 0, stream>>>(
      h, w2t, b2, out, TOKENS, DMODEL, DFF);
}

// Round 4
// 1348.079 us; speedup vs baseline: 1.0255x; 1.0255x over previous
//
#include <hip/hip_runtime.h>
#include <hip/hip_bf16.h>

// FlashFFN: y = nan_to_num(gelu_tanh(x@W1 + b1) @ W2) + b2
// Round 6: LLC-aware BAND SCHEDULING. r4/r5 counters showed the GEMMs pinned
// at FETCH=2.2GB @ 3.45 TB/s (= whole kernel duration): HBM-supply-bound from
// cache-hostile block ordering (each XCD streamed all of B per 2 block-rows).
// New mapping: bands of 256 blocks (16 m-rows x 16 n-tiles = one full GPU
// wave); XCD k (wg%8 round-robin) owns m-row-pair {2k,2k+1}. Per K-step the
// whole machine touches ~512KB (LLC-resident; ~300KB/XCD L2-resident), so B
// panels are HBM-fetched once and served 16x from cache, A row-pairs pin in
// each XCD's L2 across bands. Pipeline/schedule identical to round 5.

using bf16 = __hip_bfloat16;
typedef __attribute__((ext_vector_type(4))) float floatx4;
typedef __attribute__((ext_vector_type(8))) short shortx8;

#define TOKENS 4096   // B*S = 2*2048
#define DMODEL 4096
#define DFF    16384

__device__ __forceinline__ void gload_lds16(const void* g, void* l) {
  __builtin_amdgcn_global_load_lds(
      (const __attribute__((address_space(1))) unsigned int*)g,
      (__attribute__((address_space(3))) unsigned int*)l,
      16, 0, 0);
}

__device__ __forceinline__ unsigned lds_u32(const void* p) {
  return (unsigned)(unsigned long long)(const __attribute__((address_space(3))) char*)p;
}

__device__ __forceinline__ float gelu_tanh(float x) {
  // JAX default gelu (approximate=True, tanh form)
  float z = 0.7978845608028654f * (x + 0.044715f * x * x * x);
  float e = __expf(2.0f * z);   // inf -> t=1, 0 -> t=-1: both limits correct
  float t = 1.0f - 2.0f / (e + 1.0f);
  return 0.5f * x * (1.0f + t);
}

// ---- pre-pass: f32 -> bf16 cast (layout preserved), 8 elems/thread ----
__global__ void cvt_f32_bf16(const float* __restrict__ in, bf16* __restrict__ out) {
  int i = (blockIdx.x * blockDim.x + threadIdx.x) * 8;
  float4 a = *(const float4*)(in + i);
  float4 b = *(const float4*)(in + i + 4);
  union { shortx8 v; bf16 h[8]; } r;
  r.h[0] = __float2bfloat16(a.x); r.h[1] = __float2bfloat16(a.y);
  r.h[2] = __float2bfloat16(a.z); r.h[3] = __float2bfloat16(a.w);
  r.h[4] = __float2bfloat16(b.x); r.h[5] = __float2bfloat16(b.y);
  r.h[6] = __float2bfloat16(b.z); r.h[7] = __float2bfloat16(b.w);
  *(shortx8*)(out + i) = r.v;
}

// ---- pre-pass: transpose + cast. in [R][C] f32 -> out [C][R] bf16 ----
__global__ void transpose_cvt(const float* __restrict__ in, bf16* __restrict__ out,
                              int R, int C) {
  __shared__ float tile[64][65];
  const int c0 = blockIdx.x * 64, r0 = blockIdx.y * 64;
  const int t = threadIdx.x;
#pragma unroll
  for (int p = 0; p < 4; ++p) {
    int r = p * 16 + (t >> 4);
    int c = (t & 15) * 4;
    float4 v = *(const float4*)(in + (size_t)(r0 + r) * C + c0 + c);
    tile[r][c] = v.x; tile[r][c + 1] = v.y;
    tile[r][c + 2] = v.z; tile[r][c + 3] = v.w;
  }
  __syncthreads();
#pragma unroll
  for (int p = 0; p < 2; ++p) {
    int c = p * 32 + (t >> 3);
    int rb = (t & 7) * 8;
    union { shortx8 v; bf16 h[8]; } u;
#pragma unroll
    for (int j = 0; j < 8; ++j) u.h[j] = __float2bfloat16(tile[rb + j][c]);
    *(shortx8*)(out + (size_t)(c0 + c) * R + r0 + rb) = u.v;
  }
}

// ---- deep-pipelined GEMM: C = A @ Bt^T ----
// A [M][K] bf16 row-major, Bt [N][K] bf16 row-major. 256x256 tile, BK=32,
// 8 waves (2Mx4N), wave = 128x64 output via 8x4 16x16x32 MFMAs per K-tile.
// LDS ring: 4 slots x (256x32 A + 256x32 B). Staging swizzle (proven r2-r5):
// lane L covers row L>>2, src 16B-block (L&3)^((L>>3)&3); LDS linear.
//
// Per-tile schedule (hazard ledger unchanged from round 5):
//  phA: gloadA(t+3) | issue grpR(t) | lgkm(4) [grpP/Q(t) done, grpR flies]
//       | MFMA A | BAR1
//  phB: gloadB(t+3) | vmcnt(8) BAR2 [tile t+1 resident globally]
//       | issue grpP/Q(t+1) | lgkm(8) [grpR(t) done, grpP/Q(t+1) flies]
//       | MFMA B | BAR3
#define TILE_BODY(T, BC, BN)                                                     \
  {                                                                              \
    const int t_ = (T);                                                          \
    const unsigned aslot = As0 + (unsigned)(t_ & 3) * 16384u + a_foff;           \
    /* ---------------- phase A ---------------- */                              \
    if (t_ + 3 < NT) {                                                           \
      bf16* al = alw + ((t_ + 3) & 3) * 8192;                                    \
      const bf16* ag = agp + (size_t)(t_ + 3) * 32;                              \
      gload_lds16(ag, al);                                                       \
      gload_lds16(ag + 16 * Ks, al + 512);                                       \
    }                                                                            \
    asm volatile("ds_read_b128 %0, %1 offset:4096" : "=v"(cF[0]) : "v"(aslot)); \
    asm volatile("ds_read_b128 %0, %1 offset:5120" : "=v"(cF[1]) : "v"(aslot)); \
    asm volatile("ds_read_b128 %0, %1 offset:6144" : "=v"(cF[2]) : "v"(aslot)); \
    asm volatile("ds_read_b128 %0, %1 offset:7168" : "=v"(cF[3]) : "v"(aslot)); \
    asm volatile("s_waitcnt lgkmcnt(4)");                                        \
    __builtin_amdgcn_sched_barrier(0);                                           \
    __builtin_amdgcn_s_setprio(1);                                               \
    _Pragma("unroll")                                                            \
    for (int mi = 0; mi < 4; ++mi)                                               \
      _Pragma("unroll")                                                          \
      for (int ni = 0; ni < 4; ++ni)                                             \
        acc[mi][ni] = __builtin_amdgcn_mfma_f32_16x16x32_bf16(                   \
            aF[mi], bB[BC][ni], acc[mi][ni], 0, 0, 0);                           \
    __builtin_amdgcn_s_setprio(0);                                               \
    __builtin_amdgcn_sched_barrier(0);                                           \
    __builtin_amdgcn_s_barrier(); /* BAR1 */                                     \
    /* ---------------- phase B ---------------- */                              \
    if (t_ + 3 < NT) {                                                           \
      bf16* bl = blw + ((t_ + 3) & 3) * 8192;                                    \
      const bf16* bg = bgp + (size_t)(t_ + 3) * 32;                              \
      gload_lds16(bg, bl);                                                       \
      gload_lds16(bg + 16 * Ks, bl + 512);                                       \
    }                                                                            \
    if (t_ + 1 < NT) {                                                           \
      if (t_ + 3 < NT)      asm volatile("s_waitcnt vmcnt(8)");                  \
      else if (t_ + 2 < NT) asm volatile("s_waitcnt vmcnt(4)");                  \
      else                  asm volatile("s_waitcnt vmcnt(0)");                  \
      __builtin_amdgcn_s_barrier(); /* BAR2: tile t+1 resident globally */       \
      const unsigned an = As0 + (unsigned)((t_ + 1) & 3) * 16384u + a_foff;      \
      const unsigned bn = Bs0 + (unsigned)((t_ + 1) & 3) * 16384u + b_foff;      \
      asm volatile("ds_read_b128 %0, %1 offset:0"    : "=v"(aF[0]) : "v"(an));   \
      asm volatile("ds_read_b128 %0, %1 offset:1024" : "=v"(aF[1]) : "v"(an));   \
      asm volatile("ds_read_b128 %0, %1 offset:2048" : "=v"(aF[2]) : "v"(an));   \
      asm volatile("ds_read_b128 %0, %1 offset:3072" : "=v"(aF[3]) : "v"(an));   \
      asm volatile("ds_read_b128 %0, %1 offset:0"    : "=v"(bB[BN][0]) : "v"(bn)); \
      asm volatile("ds_read_b128 %0, %1 offset:1024" : "=v"(bB[BN][1]) : "v"(bn)); \
      asm volatile("ds_read_b128 %0, %1 offset:2048" : "=v"(bB[BN][2]) : "v"(bn)); \
      asm volatile("ds_read_b128 %0, %1 offset:3072" : "=v"(bB[BN][3]) : "v"(bn)); \
      asm volatile("s_waitcnt lgkmcnt(8)");                                      \
    } else {                                                                     \
      asm volatile("s_waitcnt lgkmcnt(0)");                                      \
    }                                                                            \
    __builtin_amdgcn_sched_barrier(0);                                           \
    __builtin_amdgcn_s_setprio(1);                                               \
    _Pragma("unroll")                                                            \
    for (int mi = 0; mi < 4; ++mi)                                               \
      _Pragma("unroll")                                                          \
      for (int ni = 0; ni < 4; ++ni)                                             \
        acc[4 + mi][ni] = __builtin_amdgcn_mfma_f32_16x16x32_bf16(               \
            cF[mi], bB[BC][ni], acc[4 + mi][ni], 0, 0, 0);                       \
    __builtin_amdgcn_s_setprio(0);                                               \
    __builtin_amdgcn_sched_barrier(0);                                           \
    __builtin_amdgcn_s_barrier(); /* BAR3 */                                     \
  }

template <int FUSE_GELU>
__launch_bounds__(512, 2)
__global__ void gemm_bt(const bf16* __restrict__ A, const bf16* __restrict__ Bt,
                        const float* __restrict__ bias, void* __restrict__ Cout,
                        int M, int N, int K) {
  __shared__ __align__(16) bf16 As[4 * 256 * 32];   // 64 KiB
  __shared__ __align__(16) bf16 Bs[4 * 256 * 32];   // 64 KiB

  const int tid = threadIdx.x;
  const int wave = tid >> 6;
  const int lane = tid & 63;

  // LLC-aware band mapping. M/256 == 16 for both GEMMs. Band = 256 blocks
  // (16 m-rows x 16 n-tiles) = one full GPU occupancy wave. Within a band,
  // XCD k (wg%8 round-robin dispatch) owns m-row-pair {2k, 2k+1}:
  //   wg8 = wg&255: xcd = wg8&7, slot = wg8>>3 (0..31)
  //   mrow = 2*xcd + (slot&1), ntile = (wg>>8)*16 + (slot>>1)
  // Bijective: (xcd, slot&1) <-> mrow 0..15; slot>>1 <-> 16 n per band.
  const int wg8  = blockIdx.x & 255;
  const int xcd  = wg8 & 7;
  const int slot = wg8 >> 3;
  const int m0 = (2 * xcd + (slot & 1)) * 256;
  const int n0 = ((blockIdx.x >> 8) * 16 + (slot >> 1)) * 256;

  const size_t Ks = (size_t)K;
  const int NT = K >> 5;   // # of BK=32 K-tiles (128 or 512 here; even)

  const int srow = lane >> 2;
  const int kbsw = (lane & 3) ^ ((lane >> 3) & 3);
  const bf16* agp = A  + (size_t)(m0 + wave * 32 + srow) * Ks + kbsw * 8;
  const bf16* bgp = Bt + (size_t)(n0 + wave * 32 + srow) * Ks + kbsw * 8;
  bf16* const alw = As + wave * 1024;   // 32 rows * 32 cols
  bf16* const blw = Bs + wave * 1024;

  // fragment-read constants (16x16x32 MFMA)
  const int wr = wave >> 2, wc = wave & 3;
  const int wm = wr * 128, wn = wc * 64;
  const int fr = lane & 15;            // row within 16-row fragment
  const int q  = lane >> 4;            // which 8-elem k-block (0..3)
  const int sf = (fr >> 1) & 3;        // matches staging swizzle s(row)
  const int fk = (q ^ sf) * 8;

  const unsigned As0 = lds_u32(As);
  const unsigned Bs0 = lds_u32(Bs);
  const unsigned a_foff = (unsigned)((wm + fr) * 32 + fk) * 2;
  const unsigned b_foff = (unsigned)((wn + fr) * 32 + fk) * 2;

  floatx4 acc[8][4] = {};
  shortx8 aF[4];      // grpP: A mi0-3 of current tile
  shortx8 cF[4];      // grpR: A mi4-7 of current tile
  shortx8 bB[2][4];   // grpQ: B ni0-3, register double-buffer across tiles

  // prologue: stage K-tiles 0..2 into ring slots 0..2 (12 loads/thread)
#pragma unroll
  for (int pt = 0; pt < 3; ++pt) {
    bf16* al = alw + pt * 8192;
    bf16* bl = blw + pt * 8192;
    const bf16* ag = agp + (size_t)pt * 32;
    const bf16* bg = bgp + (size_t)pt * 32;
    gload_lds16(ag, al);
    gload_lds16(ag + 16 * Ks, al + 512);
    gload_lds16(bg, bl);
    gload_lds16(bg + 16 * Ks, bl + 512);
  }
  asm volatile("s_waitcnt vmcnt(8)");   // tile 0 resident (own loads)
  __builtin_amdgcn_s_barrier();         // tile 0 resident globally
  {
    const unsigned a0 = As0 + a_foff;   // slot 0
    const unsigned b0 = Bs0 + b_foff;
    asm volatile("ds_read_b128 %0, %1 offset:0"    : "=v"(aF[0]) : "v"(a0));
    asm volatile("ds_read_b128 %0, %1 offset:1024" : "=v"(aF[1]) : "v"(a0));
    asm volatile("ds_read_b128 %0, %1 offset:2048" : "=v"(aF[2]) : "v"(a0));
    asm volatile("ds_read_b128 %0, %1 offset:3072" : "=v"(aF[3]) : "v"(a0));
    asm volatile("ds_read_b128 %0, %1 offset:0"    : "=v"(bB[0][0]) : "v"(b0));
    asm volatile("ds_read_b128 %0, %1 offset:1024" : "=v"(bB[0][1]) : "v"(b0));
    asm volatile("ds_read_b128 %0, %1 offset:2048" : "=v"(bB[0][2]) : "v"(b0));
    asm volatile("ds_read_b128 %0, %1 offset:3072" : "=v"(bB[0][3]) : "v"(b0));
  }

  for (int t = 0; t < NT; t += 2) {
    TILE_BODY(t,     0, 1)
    TILE_BODY(t + 1, 1, 0)
  }

  // epilogue. C/D layout (m89/m91): col = lane&15, row = (lane>>4)*4 + reg
  const int col0 = n0 + wn + fr;
  const int row0 = m0 + wm + (lane >> 4) * 4;
#pragma unroll
  for (int ni = 0; ni < 4; ++ni) {
    const int col = col0 + ni * 16;
    const float bv = bias[col];
#pragma unroll
    for (int mi = 0; mi < 8; ++mi) {
#pragma unroll
      for (int r = 0; r < 4; ++r) {
        const int row = row0 + mi * 16 + r;
        float v = acc[mi][ni][r];
        if (FUSE_GELU) {
          v = gelu_tanh(v + bv);
          ((bf16*)Cout)[(size_t)row * N + col] = __float2bfloat16(v);
        } else {
          if (!isfinite(v)) v = 0.0f;   // nan_to_num BEFORE +b2
          ((float*)Cout)[(size_t)row * N + col] = v + bv;
        }
      }
    }
  }
}

extern "C" void kernel_launch(void* const* d_in, const int* in_sizes, int n_in,
                              void* d_out, int out_size, void* d_ws, size_t ws_size,
                              hipStream_t stream) {
  const float* x  = (const float*)d_in[0];
  const float* W1 = (const float*)d_in[1];
  const float* b1 = (const float*)d_in[2];
  const float* W2 = (const float*)d_in[3];
  const float* b2 = (const float*)d_in[4];
  float* out = (float*)d_out;

  // workspace layout (bf16): xb 32MB @0, h 128MB @32MB, w1t 128MB @160MB,
  // w2t 128MB @288MB (total 416 MB)
  char* ws = (char*)d_ws;
  bf16* xb  = (bf16*)(ws);
  bf16* h   = (bf16*)(ws + (size_t)32  * 1024 * 1024);
  bf16* w1t = (bf16*)(ws + (size_t)160 * 1024 * 1024);
  bf16* w2t = (bf16*)(ws + (size_t)288 * 1024 * 1024);

  cvt_f32_bf16<<<(TOKENS * DMODEL / 8) / 256, 256, 0, stream>>>(x, xb);
  transpose_cvt<<<dim3(DFF / 64, DMODEL / 64), 256, 0, stream>>>(W1, w1t, DMODEL, DFF);
  transpose_cvt<<<dim3(DMODEL / 64, DFF / 64), 256, 0, stream>>>(W2, w2t, DFF, DMODEL);

  // GEMM1: h = gelu(x @ W1 + b1)   [4096 x 16384] bf16
  gemm_bt<1><<<dim3((DFF / 256) * (TOKENS / 256)), 512, 0, stream>>>(
      xb, w1t, b1, h, TOKENS, DFF, DMODEL);

  // GEMM2: out = nan_guard(h @ W2) + b2   [4096 x 4096] f32
  gemm_bt<0><<<dim3((DMODEL / 256) * (TOKENS / 256)), 512, 0, stream>>>(
      h, w2t, b2, out, TOKENS, DMODEL, DFF);
}